// Round 1
// baseline (194.799 us; speedup 1.0000x reference)
//
#include <hip/hip_runtime.h>

#define LAMBDA_COORD 5.0f
#define LAMBDA_NOOBJ 0.5f

// 802816 cells; preds 30 f32/cell (120 B), targets 25 f32/cell (100 B).
//
// v2: the per-lane whole-cell load pattern was uncoalesced (each dwordx4
// touched 64 distinct cache lines -> address-pipe bound at 2.6 TB/s
// effective, 16% HBM). Now each 256-thread block stages its 256 cells'
// contiguous pred/target slabs into LDS with lane-linear
// global_load_lds_dwordx4 (fully coalesced 1 KiB/instr streaming), then
// each lane reads its cell from LDS (stride-30/25 dwords: <=4-way
// conflicts, LDS is nowhere near its 69 TB/s ceiling).
// LDS 56.3 KiB -> 2 blocks/CU; ~14 outstanding 1KiB loads per wave gives
// ample MLP despite 25% occupancy.

typedef float f4u __attribute__((ext_vector_type(4), aligned(4)));
typedef float f2u __attribute__((ext_vector_type(2), aligned(4)));

__global__ void zero_out_kernel(float* out, int n) {
    int i = blockIdx.x * blockDim.x + threadIdx.x;
    if (i < n) out[i] = 0.0f;
}

__device__ __forceinline__ void gld16(const float* g, float* l) {
    // async global->LDS, 16 B per lane; LDS dest must be (and is)
    // wave-uniform base + lane*16 (lane-linear staging layout).
    __builtin_amdgcn_global_load_lds(
        (const __attribute__((address_space(1))) void*)g,
        (__attribute__((address_space(3))) void*)l,
        16, 0, 0);
}

__global__ __launch_bounds__(256, 2) void yolo_loss_kernel(
    const float* __restrict__ preds, const float* __restrict__ targets,
    float* __restrict__ out, int n_cells)
{
    __shared__ float sp[256 * 30];   // 30720 B, block's pred slab
    __shared__ float st[256 * 25];   // 25600 B, block's target slab
    __shared__ float s_part[4];

    const int tid = threadIdx.x;
    const int block0 = blockIdx.x * 256;
    const bool full = (block0 + 256) <= n_cells;   // block-uniform

    float loss = 0.0f;

    if (full) {
        const float* pblk = preds + (size_t)block0 * 30;
        const float* tblk = targets + (size_t)block0 * 25;

        // stage preds: 1920 float4 (7.5 iters; tail is wave-whole)
        #pragma unroll
        for (int j = 0; j < 8; ++j) {
            int i = tid + j * 256;
            if (i < 1920) gld16(pblk + i * 4, sp + i * 4);
        }
        // stage targets: 1600 float4 (6.25 iters; tail is wave-whole)
        #pragma unroll
        for (int j = 0; j < 7; ++j) {
            int i = tid + j * 256;
            if (i < 1600) gld16(tblk + i * 4, st + i * 4);
        }
        // __syncthreads() drains vmcnt (compiler emits the waitcnt) so all
        // global_load_lds data is visible block-wide.
        __syncthreads();

        const float* P = sp + tid * 30;
        const float* T = st + tid * 25;

        float q0 = P[0], q1 = P[1], q2 = P[2], q3 = P[3], q4 = P[4];
        float q5 = P[5], q6 = P[6], q7 = P[7], q8 = P[8], q9 = P[9];

        // jnp.argmax picks first index on tie -> box1 only on strict greater.
        bool pick1 = q5 > q0;
        float b0 = pick1 ? q5 : q0;
        float b1 = pick1 ? q6 : q1;
        float b2 = pick1 ? q7 : q2;
        float b3 = pick1 ? q8 : q3;
        float b4 = pick1 ? q9 : q4;

        float t0 = T[0];
        float d1 = b1 - T[1], d2 = b2 - T[2], d3 = b3 - T[3], d4 = b4 - T[4];
        float box_loss = d1 * d1 + d2 * d2 + d3 * d3 + d4 * d4;
        float dpc = b0 - t0;
        float pc_loss = dpc * dpc;

        float cl = 0.0f;
        #pragma unroll
        for (int k = 0; k < 20; ++k) {
            float d = P[10 + k] - T[5 + k];
            cl += d * d;
        }

        float obj_term = LAMBDA_COORD * box_loss + pc_loss + cl;
        float noobj_term = LAMBDA_NOOBJ * (q0 * q0 + q5 * q5);
        loss = (t0 == 1.0f) ? obj_term : noobj_term;
    } else {
        // ragged tail block (never taken for n_cells % 256 == 0): direct loads
        const int c = block0 + tid;
        if (c < n_cells) {
            const float* pbase = preds + (size_t)c * 30;
            const float* tbase = targets + (size_t)c * 25;
            const f4u* pp = (const f4u*)pbase;
            const f4u* tp = (const f4u*)tbase;

            f4u P0 = pp[0], P1 = pp[1], P2 = pp[2], P3 = pp[3];
            f4u P4 = pp[4], P5 = pp[5], P6 = pp[6];
            f2u P7 = *(const f2u*)(pbase + 28);
            f4u T0 = tp[0], T1 = tp[1], T2 = tp[2], T3 = tp[3];
            f4u T4 = tp[4], T5 = tp[5];
            float t24 = tbase[24];

            float p0 = P0.x, p5c = P1.y;
            bool pick1 = p5c > p0;
            float b0 = pick1 ? p5c  : p0;
            float b1 = pick1 ? P1.z : P0.y;
            float b2 = pick1 ? P1.w : P0.z;
            float b3 = pick1 ? P2.x : P0.w;
            float b4 = pick1 ? P2.y : P1.x;

            float t0 = T0.x;
            float d1 = b1 - T0.y, d2 = b2 - T0.z, d3 = b3 - T0.w, d4 = b4 - T1.x;
            float box_loss = d1 * d1 + d2 * d2 + d3 * d3 + d4 * d4;
            float dpc = b0 - t0;
            float pc_loss = dpc * dpc;

            float cl = 0.0f, d;
            d = P2.z - T1.y; cl += d * d;
            d = P2.w - T1.z; cl += d * d;
            d = P3.x - T1.w; cl += d * d;
            d = P3.y - T2.x; cl += d * d;
            d = P3.z - T2.y; cl += d * d;
            d = P3.w - T2.z; cl += d * d;
            d = P4.x - T2.w; cl += d * d;
            d = P4.y - T3.x; cl += d * d;
            d = P4.z - T3.y; cl += d * d;
            d = P4.w - T3.z; cl += d * d;
            d = P5.x - T3.w; cl += d * d;
            d = P5.y - T4.x; cl += d * d;
            d = P5.z - T4.y; cl += d * d;
            d = P5.w - T4.z; cl += d * d;
            d = P6.x - T4.w; cl += d * d;
            d = P6.y - T5.x; cl += d * d;
            d = P6.z - T5.y; cl += d * d;
            d = P6.w - T5.z; cl += d * d;
            d = P7.x - T5.w; cl += d * d;
            d = P7.y - t24;  cl += d * d;

            float obj_term = LAMBDA_COORD * box_loss + pc_loss + cl;
            float noobj_term = LAMBDA_NOOBJ * (p0 * p0 + p5c * p5c);
            loss = (t0 == 1.0f) ? obj_term : noobj_term;
        }
    }

    // wave (64-lane) shuffle reduction
    #pragma unroll
    for (int off = 32; off > 0; off >>= 1)
        loss += __shfl_down(loss, off, 64);

    const int wave = tid >> 6;
    if ((tid & 63) == 0) s_part[wave] = loss;
    __syncthreads();
    if (tid == 0) {
        float s = s_part[0] + s_part[1] + s_part[2] + s_part[3];
        atomicAdd(out, s);
    }
}

extern "C" void kernel_launch(void* const* d_in, const int* in_sizes, int n_in,
                              void* d_out, int out_size, void* d_ws, size_t ws_size,
                              hipStream_t stream) {
    const float* preds   = (const float*)d_in[0];
    const float* targets = (const float*)d_in[1];
    float* out = (float*)d_out;

    const int n_cells = in_sizes[0] / 30;   // 802816 (multiple of 256)

    // d_out is poisoned (0xAA) before every timed replay — zero it on-stream.
    zero_out_kernel<<<(out_size + 255) / 256, 256, 0, stream>>>(out, out_size);

    const int grid = (n_cells + 255) / 256; // 3136
    yolo_loss_kernel<<<grid, 256, 0, stream>>>(preds, targets, out, n_cells);
}